// Round 5
// baseline (503.820 us; speedup 1.0000x reference)
//
#include <hip/hip_runtime.h>
#include <cstdint>
#include <cstddef>

typedef unsigned short u16;
typedef __attribute__((ext_vector_type(4))) float f32x4;
typedef __attribute__((ext_vector_type(8))) short s16x8;

#define D_EMB 1024
#define NSEQ 1024
#define NB 8
#define NH 16
#define HS 64
#define DFF 4096
#define MTOT (NB*NSEQ)

__device__ __forceinline__ u16 f2bf(float f){
  unsigned u = __float_as_uint(f);
  u += 0x7FFFu + ((u >> 16) & 1u);     // round-to-nearest-even
  return (u16)(u >> 16);
}

__device__ __forceinline__ void gload_lds16(const void* g, void* l){
  __builtin_amdgcn_global_load_lds((const __attribute__((address_space(1))) void*)g,
                                   (__attribute__((address_space(3))) void*)l, 16, 0, 0);
}

// ---------------- tiled transpose + fp32->bf16 convert ----------------
__global__ void transpose_cvt(const float* __restrict__ in, u16* __restrict__ out,
                              int R, int C, size_t inStride, size_t outStride){
  __shared__ float t[32][33];
  const float* ip = in + (size_t)blockIdx.z * inStride;
  u16* op = out + (size_t)blockIdx.z * outStride;
  int c0 = blockIdx.x * 32, r0 = blockIdx.y * 32;
  int tx = threadIdx.x, ty = threadIdx.y;
#pragma unroll
  for (int j = 0; j < 32; j += 8)
    t[ty + j][tx] = ip[(size_t)(r0 + ty + j) * C + (c0 + tx)];
  __syncthreads();
#pragma unroll
  for (int j = 0; j < 32; j += 8)
    op[(size_t)(c0 + ty + j) * R + (r0 + tx)] = f2bf(t[tx][ty + j]);
}

// ---------------- LayerNorm (fp32 in, bf16 out) ----------------
__global__ __launch_bounds__(256) void ln_kernel(const float* __restrict__ x,
    const float* __restrict__ g, const float* __restrict__ bb, u16* __restrict__ out){
  int row = blockIdx.x;
  const float* xr = x + (size_t)row * D_EMB;
  int c = threadIdx.x * 4;
  f32x4 v = *(const f32x4*)(xr + c);
  float s1 = v[0] + v[1] + v[2] + v[3];
  float s2 = v[0]*v[0] + v[1]*v[1] + v[2]*v[2] + v[3]*v[3];
#pragma unroll
  for (int m = 32; m > 0; m >>= 1){ s1 += __shfl_xor(s1, m); s2 += __shfl_xor(s2, m); }
  __shared__ float ps1[4], ps2[4];
  int w = threadIdx.x >> 6;
  if ((threadIdx.x & 63) == 0){ ps1[w] = s1; ps2[w] = s2; }
  __syncthreads();
  s1 = ps1[0] + ps1[1] + ps1[2] + ps1[3];
  s2 = ps2[0] + ps2[1] + ps2[2] + ps2[3];
  float mu = s1 * (1.f / D_EMB);
  float var = s2 * (1.f / D_EMB) - mu * mu;
  float rs = rsqrtf(var + 1e-5f);
  ushort4 o;
  o.x = f2bf((v[0]-mu)*rs*g[c+0] + bb[c+0]);
  o.y = f2bf((v[1]-mu)*rs*g[c+1] + bb[c+1]);
  o.z = f2bf((v[2]-mu)*rs*g[c+2] + bb[c+2]);
  o.w = f2bf((v[3]-mu)*rs*g[c+3] + bb[c+3]);
  *(ushort4*)(out + (size_t)row * D_EMB + c) = o;
}

// ================= 256x256 8-phase GEMM (T2+T3+T4+T5) =================
// C = A[M,K] * Bt[N,K]^T. 512 thr = 8 waves. BK=64 split in 2 k-halves.
// Stage order per tile: Ak0,Bk0,Ak1,Bk1 (one per phase, 1 tile ahead).
// Counted vmcnt certifies the half needed 2 phases later. LAST tile has no
// prefetch: mid-tile wait must drain to 0 there (round-4 bug: vmcnt(4) was
// a no-op with only 4 outstanding -> last k-half read uncertified).
template<int MODE, int BNT>
__global__ __launch_bounds__(512) void gemm256(
    const u16* __restrict__ A, const u16* __restrict__ Bt,
    int M, int N, int K,
    const float* __restrict__ bias0, const float* __restrict__ bias1,
    const float* __restrict__ bias2, const float* __restrict__ resid,
    void* __restrict__ o0, void* __restrict__ o1, void* __restrict__ o2)
{
  constexpr int BMT = 256;
  constexpr int WCN = BNT/64, WRN = 8/WCN;      // wave grid
  constexpr int WROWS = BMT/WRN;                // rows per wave (128 or 64)
  constexpr int RF = WROWS/16, RH = RF/2;       // row frags / per phase
  constexpr int ALD = 2, BLD = (BNT*32)/(512*8);// 16B loads per thr per half
  constexpr int AHALF = BMT*32, BHALF = BNT*32; // u16 per (buf,kh)
  extern __shared__ u16 lds[];
  u16* const Ab = lds;
  u16* const Bb = lds + 4*AHALF;

  const int tid = threadIdx.x;
  const int wid = tid>>6, lane = tid&63, lr = lane&15, lg = lane>>4;
  const int wr = wid/WCN, wc = wid%WCN;

  // XCD swizzle (nwg always divisible by 8 here)
  const int gx = gridDim.x;
  const int nwg = gx * gridDim.y;
  const int bid = blockIdx.x + blockIdx.y*gx;
  const int wg = (bid&7)*(nwg>>3) + (bid>>3);
  const int m0 = (wg % gx) * BMT;
  const int n0 = (wg / gx) * BNT;

  const int nkt = K/64;
  const int srow = tid>>2;                    // 0..127
  const int sl = (tid&3) ^ ((tid>>2)&3);      // inverse-swizzled source chunk

  auto stageA = [&](int nb, int kt1, int kh){
    const u16* src = A + (size_t)m0 * K + (size_t)kt1*64 + kh*32 + sl*8;
    u16* dst = Ab + (nb*2 + kh)*AHALF + tid*8;
#pragma unroll
    for (int r = 0; r < ALD; ++r)
      gload_lds16(src + (size_t)(r*128 + srow)*K, dst + r*4096);
  };
  auto stageB = [&](int nb, int kt1, int kh){
    const u16* src = Bt + (size_t)n0 * K + (size_t)kt1*64 + kh*32 + sl*8;
    u16* dst = Bb + (nb*2 + kh)*BHALF + tid*8;
#pragma unroll
    for (int r = 0; r < BLD; ++r)
      gload_lds16(src + (size_t)(r*128 + srow)*K, dst + r*4096);
  };
  auto rdA = [&](int cur, int kh, int fm) -> s16x8 {
    const int row = wr*WROWS + fm*16 + lr;
    return *(const s16x8*)&Ab[(cur*2+kh)*AHALF + row*32 + ((lg ^ (row&3))<<3)];
  };
  auto rdB = [&](int cur, int kh, int fn) -> s16x8 {
    const int row = wc*64 + fn*16 + lr;
    return *(const s16x8*)&Bb[(cur*2+kh)*BHALF + row*32 + ((lg ^ (row&3))<<3)];
  };
  auto waitv = [&](){
    if constexpr (ALD + BLD == 4) asm volatile("s_waitcnt vmcnt(4)" ::: "memory");
    else                          asm volatile("s_waitcnt vmcnt(3)" ::: "memory");
  };

  f32x4 acc[RF][4];
#pragma unroll
  for (int i = 0; i < RF; i++)
#pragma unroll
    for (int j = 0; j < 4; j++) acc[i][j] = {0.f,0.f,0.f,0.f};

  // prologue: full tile 0 into buf 0; certify k0 halves; k1 stays in flight
  stageA(0,0,0); stageB(0,0,0); stageA(0,0,1); stageB(0,0,1);
  waitv();
  __builtin_amdgcn_s_barrier();

  s16x8 bf[4];
  for (int kt = 0; kt < nkt; ++kt){
    const int cur = kt&1, nb = cur^1;
    const bool st = (kt+1 < nkt);
#pragma unroll
    for (int kh = 0; kh < 2; ++kh){
      // ---- phase (kh, rh=0): reads this kh's A-low + B frags ----
      s16x8 af[RH];
#pragma unroll
      for (int j = 0; j < RH; ++j) af[j] = rdA(cur, kh, j);
#pragma unroll
      for (int fn = 0; fn < 4; ++fn) bf[fn] = rdB(cur, kh, fn);
      if (st){ if (kh == 0) stageA(nb, kt+1, 0); else stageA(nb, kt+1, 1); }
      __builtin_amdgcn_s_barrier();
      asm volatile("s_waitcnt lgkmcnt(0)" ::: "memory");
      __builtin_amdgcn_sched_barrier(0);
      __builtin_amdgcn_s_setprio(1);
#pragma unroll
      for (int j = 0; j < RH; ++j)
#pragma unroll
        for (int fn = 0; fn < 4; ++fn)
          acc[j][fn] = __builtin_amdgcn_mfma_f32_16x16x32_bf16(af[j], bf[fn], acc[j][fn], 0, 0, 0);
      __builtin_amdgcn_s_setprio(0);
      __builtin_amdgcn_s_barrier();
      // ---- phase (kh, rh=1): reads this kh's A-high, reuses bf ----
#pragma unroll
      for (int j = 0; j < RH; ++j) af[j] = rdA(cur, kh, RH + j);
      if (st){ if (kh == 0) stageB(nb, kt+1, 0); else stageB(nb, kt+1, 1); }
      __builtin_amdgcn_s_barrier();
      asm volatile("s_waitcnt lgkmcnt(0)" ::: "memory");
      __builtin_amdgcn_sched_barrier(0);
      __builtin_amdgcn_s_setprio(1);
#pragma unroll
      for (int j = 0; j < RH; ++j)
#pragma unroll
        for (int fn = 0; fn < 4; ++fn)
          acc[RH+j][fn] = __builtin_amdgcn_mfma_f32_16x16x32_bf16(af[j], bf[fn], acc[RH+j][fn], 0, 0, 0);
      __builtin_amdgcn_s_setprio(0);
      if (kh == 0){
        // certify this tile's k1 half. Steady state: 2*(ALD+BLD) in flight,
        // counted wait drains exactly Ak1,Bk1. Last tile (no prefetch): only
        // Ak1,Bk1 outstanding -> must drain to 0 (round-4 bug fix).
        if (st) waitv();
        else    asm volatile("s_waitcnt vmcnt(0)" ::: "memory");
      } else {
        if (st) waitv();           // certify next tile's k0 half
        // last tile: nothing outstanding, no wait needed
      }
      __builtin_amdgcn_s_barrier();
    }
  }

  // epilogue
#pragma unroll
  for (int fm = 0; fm < RF; fm++){
    const int gmb = m0 + wr*WROWS + fm*16 + lg*4;
#pragma unroll
    for (int fn = 0; fn < 4; fn++){
      const int gn = n0 + wc*64 + fn*16 + lr;
#pragma unroll
      for (int i = 0; i < 4; i++){
        const int gm = gmb + i;
        float v = acc[fm][fn][i];
        if (MODE == 0){
          const int cls = gn >> 10, nn = gn & 1023;
          if (cls == 0)      ((u16*)o0)[(size_t)gm * D_EMB + nn] = f2bf(v + bias0[nn]);
          else if (cls == 1) ((u16*)o1)[(size_t)gm * D_EMB + nn] = f2bf(v + bias1[nn]);
          else {
            const int hh = nn >> 6, ss = nn & 63, bb = gm >> 10, tt = gm & 1023;
            ((u16*)o2)[(((size_t)(bb * NH + hh)) * HS + ss) * NSEQ + tt] = f2bf(v + bias2[nn]);
          }
        } else if (MODE == 1){
          ((float*)o0)[(size_t)gm * N + gn] = resid[(size_t)gm * N + gn] + v + bias0[gn];
        } else {
          float y = v + bias0[gn];
          y = y > 0.f ? y : 0.01f * y;
          ((u16*)o0)[(size_t)gm * N + gn] = f2bf(y);
        }
      }
    }
  }
}

// ---------------- fallback GEMM (proven round-3 128x128) ----------------
#define BM 128
#define BN 128
#define BK 32
template<int MODE>
__global__ __launch_bounds__(256) void gemm_bt(
    const u16* __restrict__ A, const u16* __restrict__ Bt,
    int M, int N, int K,
    const float* __restrict__ bias0, const float* __restrict__ bias1,
    const float* __restrict__ bias2, const float* __restrict__ resid,
    void* __restrict__ o0, void* __restrict__ o1, void* __restrict__ o2)
{
  __shared__ alignas(16) u16 Al[2][BM*BK];
  __shared__ alignas(16) u16 Bl[2][BN*BK];
  const int tid = threadIdx.x;
  const int m0 = blockIdx.x * BM, n0 = blockIdx.y * BN;
  const int wid = tid >> 6, lane = tid & 63;
  const int wm = (wid >> 1) * 64, wn = (wid & 1) * 64;
  const int lr = lane & 15, lg = lane >> 4;

  f32x4 acc[4][4];
#pragma unroll
  for (int i = 0; i < 4; i++)
#pragma unroll
    for (int j = 0; j < 4; j++) acc[i][j] = {0.f,0.f,0.f,0.f};

  const int nk = K / BK;
  const int arow = tid >> 2, akg = tid & 3;

  auto stage = [&](int bufi, int kt){
    const int k0 = kt * BK;
    const u16* ap = A  + (size_t)(m0 + arow) * K + k0 + akg * 8;
    gload_lds16(ap,                  &Al[bufi][tid * 8]);
    gload_lds16(ap + (size_t)64 * K, &Al[bufi][2048 + tid * 8]);
    const u16* bp = Bt + (size_t)(n0 + arow) * K + k0 + akg * 8;
    gload_lds16(bp,                  &Bl[bufi][tid * 8]);
    gload_lds16(bp + (size_t)64 * K, &Bl[bufi][2048 + tid * 8]);
  };

  stage(0, 0);
  for (int kt = 0; kt < nk; ++kt){
    __syncthreads();
    if (kt + 1 < nk) stage((kt + 1) & 1, kt + 1);
    const int bufi = kt & 1;
    s16x8 af[4], bfr[4];
#pragma unroll
    for (int i = 0; i < 4; i++){
      af[i]  = *(const s16x8*)&Al[bufi][(wm + i*16 + lr) * BK + lg * 8];
      bfr[i] = *(const s16x8*)&Bl[bufi][(wn + i*16 + lr) * BK + lg * 8];
    }
#pragma unroll
    for (int i = 0; i < 4; i++)
#pragma unroll
      for (int j = 0; j < 4; j++)
        acc[i][j] = __builtin_amdgcn_mfma_f32_16x16x32_bf16(af[i], bfr[j], acc[i][j], 0, 0, 0);
  }

#pragma unroll
  for (int fm = 0; fm < 4; fm++){
    const int gmb = m0 + wm + fm * 16 + lg * 4;
#pragma unroll
    for (int fn = 0; fn < 4; fn++){
      const int gn = n0 + wn + fn * 16 + lr;
#pragma unroll
      for (int i = 0; i < 4; i++){
        const int gm = gmb + i;
        float v = acc[fm][fn][i];
        if (MODE == 0){
          const int cls = gn >> 10, nn = gn & 1023;
          if (cls == 0)      ((u16*)o0)[(size_t)gm * D_EMB + nn] = f2bf(v + bias0[nn]);
          else if (cls == 1) ((u16*)o1)[(size_t)gm * D_EMB + nn] = f2bf(v + bias1[nn]);
          else {
            const int hh = nn >> 6, ss = nn & 63, bb = gm >> 10, tt = gm & 1023;
            ((u16*)o2)[(((size_t)(bb * NH + hh)) * HS + ss) * NSEQ + tt] = f2bf(v + bias2[nn]);
          }
        } else if (MODE == 1){
          ((float*)o0)[(size_t)gm * N + gn] = resid[(size_t)gm * N + gn] + v + bias0[gn];
        } else {
          float y = v + bias0[gn];
          y = y > 0.f ? y : 0.01f * y;
          ((u16*)o0)[(size_t)gm * N + gn] = f2bf(y);
        }
      }
    }
  }
}

// ---------------- flash attention (round-3, unchanged) ----------------
__global__ __launch_bounds__(256) void attn_kernel(
    const u16* __restrict__ Qb, const u16* __restrict__ Kb, const u16* __restrict__ VT,
    u16* __restrict__ attnC)
{
  const int bid = blockIdx.x;
  const int bh = bid & 127, qt = bid >> 7;
  const int b = bh >> 4, h = bh & 15;
  const int tid = threadIdx.x, w = tid >> 6, lane = tid & 63;
  const int lr = lane & 15, lg = lane >> 4;
  const int q0 = qt * 128 + w * 32;

  __shared__ alignas(16) u16 Kl[2][64*64];
  __shared__ alignas(16) u16 Vl[2][64*64];
  __shared__ alignas(16) u16 Pl[4][32][72];

  const int srow = tid >> 3, scg = tid & 7;
  const u16* kbase = Kb + (size_t)(b * NSEQ) * D_EMB + h * HS;
  const u16* vbase = VT + ((size_t)(b * NH + h)) * HS * NSEQ;

  auto stage = [&](int buf, int kt){
    const int tk = kt * 64;
#pragma unroll
    for (int p = 0; p < 2; ++p){
      const int row = srow + p * 32;
      const int sc = scg ^ (row & 7);
      gload_lds16(kbase + (size_t)(tk + row) * D_EMB + sc * 8, &Kl[buf][(p * 256 + tid) * 8]);
      gload_lds16(vbase + (size_t)row * NSEQ + tk + sc * 8,    &Vl[buf][(p * 256 + tid) * 8]);
    }
  };

  s16x8 aq[2][2];
#pragma unroll
  for (int rb = 0; rb < 2; rb++)
#pragma unroll
    for (int kh = 0; kh < 2; kh++)
      aq[rb][kh] = *(const s16x8*)(Qb + (size_t)(b * NSEQ + q0 + rb * 16 + lr) * D_EMB
                                   + h * HS + kh * 32 + lg * 8);

  float m_i[2][4], l_i[2][4];
  f32x4 zero = {0.f, 0.f, 0.f, 0.f};
  f32x4 ao[2][4];
#pragma unroll
  for (int rb = 0; rb < 2; rb++)
#pragma unroll
    for (int i = 0; i < 4; i++){ m_i[rb][i] = -1e30f; l_i[rb][i] = 0.f; ao[rb][i] = zero; }

  const float scale = 0.125f;
  const int rsw = lr & 7;

  stage(0, 0);
  for (int kt = 0; kt < NSEQ / 64; ++kt){
    __syncthreads();
    if (kt + 1 < NSEQ / 64) stage((kt + 1) & 1, kt + 1);
    const int cur = kt & 1;

    f32x4 sv[2][4];
#pragma unroll
    for (int rb = 0; rb < 2; rb++)
#pragma unroll
      for (int fn = 0; fn < 4; fn++) sv[rb][fn] = zero;
#pragma unroll
    for (int fn = 0; fn < 4; fn++){
      const int krow = fn * 16 + lr;
#pragma unroll
      for (int kh = 0; kh < 2; kh++){
        const int chunk = (kh * 4 + lg) ^ rsw;
        s16x8 kf = *(const s16x8*)&Kl[cur][krow * 64 + chunk * 8];
        sv[0][fn] = __builtin_amdgcn_mfma_f32_16x16x32_bf16(aq[0][kh], kf, sv[0][fn], 0, 0, 0);
        sv[1][fn] = __builtin_amdgcn_mfma_f32_16x16x32_bf16(aq[1][kh], kf, sv[1][fn], 0, 0, 0);
      }
    }

#pragma unroll
    for (int rb = 0; rb < 2; rb++){
      float p[4][4];
#pragma unroll
      for (int i = 0; i < 4; i++){
        float s0 = sv[rb][0][i] * scale, s1 = sv[rb][1][i] * scale;
        float s2 = sv[rb][2][i] * scale, s3 = sv[rb][3][i] * scale;
        float rmax = fmaxf(fmaxf(s0, s1), fmaxf(s2, s3));
#pragma unroll
        for (int mm = 8; mm > 0; mm >>= 1) rmax = fmaxf(rmax, __shfl_xor(rmax, mm));
        float mnew = fmaxf(m_i[rb][i], rmax);
        float fac = __expf(m_i[rb][i] - mnew);
        float p0 = __expf(s0 - mnew), p1 = __expf(s1 - mnew);
        float p2 = __expf(s2 - mnew), p3 = __expf(s3 - mnew);
        p[0][i] = p0; p[1][i] = p1; p[2][i] = p2; p[3][i] = p3;
        float rs = (p0 + p1) + (p2 + p3);
#pragma unroll
        for (int mm = 8; mm > 0; mm >>= 1) rs += __shfl_xor(rs, mm);
        l_i[rb][i] = l_i[rb][i] * fac + rs;
        m_i[rb][i] = mnew;
#pragma unroll
        for (int fn = 0; fn < 4; fn++) ao[rb][fn][i] *= fac;
      }
#pragma unroll
      for (int fn = 0; fn < 4; fn++)
#pragma unroll
        for (int i = 0; i < 4; i++)
          Pl[w][rb * 16 + lg * 4 + i][fn * 16 + lr] = f2bf(p[fn][i]);
    }

    s16x8 vf[4][2];
#pragma unroll
    for (int fn = 0; fn < 4; fn++){
      const int vrow = fn * 16 + lr;
#pragma unroll
      for (int kh = 0; kh < 2; kh++){
        const int chunk = (kh * 4 + lg) ^ rsw;
        vf[fn][kh] = *(const s16x8*)&Vl[cur][vrow * 64 + chunk * 8];
      }
    }
#pragma unroll
    for (int rb = 0; rb < 2; rb++){
      s16x8 pa0 = *(const s16x8*)&Pl[w][rb * 16 + lr][lg * 8];
      s16x8 pa1 = *(const s16x8*)&Pl[w][rb * 16 + lr][32 + lg * 8];
#pragma unroll
      for (int fn = 0; fn < 4; fn++){
        ao[rb][fn] = __builtin_amdgcn_mfma_f32_16x16x32_bf16(pa0, vf[fn][0], ao[rb][fn], 0, 0, 0);
        ao[rb][fn] = __builtin_amdgcn_mfma_f32_16x16x32_bf16(pa1, vf[fn][1], ao[rb][fn], 0, 0, 0);
      }
    }
  }

#pragma unroll
  for (int rb = 0; rb < 2; rb++)
#pragma unroll
    for (int fn = 0; fn < 4; fn++)
#pragma unroll
      for (int i = 0; i < 4; i++){
        float v = ao[rb][fn][i] / l_i[rb][i];
        attnC[(size_t)(b * NSEQ + q0 + rb * 16 + lg * 4 + i) * D_EMB + h * HS + fn * 16 + lr] = f2bf(v);
      }
}

// ---------------- host ----------------
extern "C" void kernel_launch(void* const* d_in, const int* in_sizes, int n_in,
                              void* d_out, int out_size, void* d_ws, size_t ws_size,
                              hipStream_t stream)
{
  const float* x    = (const float*)d_in[0];
  const float* Wq   = (const float*)d_in[1];
  const float* bq   = (const float*)d_in[2];
  const float* Wk   = (const float*)d_in[3];
  const float* bk   = (const float*)d_in[4];
  const float* Wv   = (const float*)d_in[5];
  const float* bv   = (const float*)d_in[6];
  const float* Wp   = (const float*)d_in[7];
  const float* bp   = (const float*)d_in[8];
  const float* W1   = (const float*)d_in[9];
  const float* b1   = (const float*)d_in[10];
  const float* W2   = (const float*)d_in[11];
  const float* b2   = (const float*)d_in[12];
  const float* ln1g = (const float*)d_in[13];
  const float* ln1b = (const float*)d_in[14];
  const float* ln2g = (const float*)d_in[15];
  const float* ln2b = (const float*)d_in[16];
  float* out = (float*)d_out;

  char* ws = (char*)d_ws;
  size_t off = 0;
  auto mk = [&](size_t bytes)->void*{ void* p = ws + off; off += (bytes + 255) & ~(size_t)255; return p; };
  u16*  h1    = (u16*) mk((size_t)MTOT * D_EMB * 2);
  u16*  Qb    = (u16*) mk((size_t)MTOT * D_EMB * 2);
  u16*  Kb    = (u16*) mk((size_t)MTOT * D_EMB * 2);
  u16*  VTb   = (u16*) mk((size_t)MTOT * D_EMB * 2);
  u16*  attnC = (u16*) mk((size_t)MTOT * D_EMB * 2);
  float* x1   = (float*)mk((size_t)MTOT * D_EMB * 4);
  u16*  h2    = (u16*) mk((size_t)MTOT * D_EMB * 2);
  u16*  ffb   = (u16*) mk((size_t)MTOT * DFF * 2);
  u16*  WqkvT = (u16*) mk((size_t)3 * D_EMB * D_EMB * 2);
  u16*  WpT   = (u16*) mk((size_t)D_EMB * D_EMB * 2);
  u16*  W1T   = (u16*) mk((size_t)D_EMB * DFF * 2);
  u16*  W2T   = (u16*) mk((size_t)D_EMB * DFF * 2);

  dim3 tb(32, 8, 1);
  transpose_cvt<<<dim3(HS/32, D_EMB/32, NH), tb, 0, stream>>>(Wq, WqkvT,                         D_EMB, HS, (size_t)D_EMB*HS, (size_t)HS*D_EMB);
  transpose_cvt<<<dim3(HS/32, D_EMB/32, NH), tb, 0, stream>>>(Wk, WqkvT + (size_t)D_EMB*D_EMB,   D_EMB, HS, (size_t)D_EMB*HS, (size_t)HS*D_EMB);
  transpose_cvt<<<dim3(HS/32, D_EMB/32, NH), tb, 0, stream>>>(Wv, WqkvT + (size_t)2*D_EMB*D_EMB, D_EMB, HS, (size_t)D_EMB*HS, (size_t)HS*D_EMB);
  transpose_cvt<<<dim3(D_EMB/32, D_EMB/32, 1), tb, 0, stream>>>(Wp, WpT,  D_EMB, D_EMB, 0, 0);
  transpose_cvt<<<dim3(DFF/32,  D_EMB/32, 1), tb, 0, stream>>>(W1, W1T,  D_EMB, DFF,   0, 0);
  transpose_cvt<<<dim3(D_EMB/32, DFF/32,  1), tb, 0, stream>>>(W2, W2T,  DFF,   D_EMB, 0, 0);

  ln_kernel<<<MTOT, 256, 0, stream>>>(x, ln1g, ln1b, h1);

  // opt-in to >64KB dynamic LDS; fall back to proven 128^2 GEMM on failure
  bool big = true;
  big &= hipFuncSetAttribute(reinterpret_cast<const void*>(&gemm256<0,256>),
                             hipFuncAttributeMaxDynamicSharedMemorySize, 131072) == hipSuccess;
  big &= hipFuncSetAttribute(reinterpret_cast<const void*>(&gemm256<2,256>),
                             hipFuncAttributeMaxDynamicSharedMemorySize, 131072) == hipSuccess;
  big &= hipFuncSetAttribute(reinterpret_cast<const void*>(&gemm256<1,128>),
                             hipFuncAttributeMaxDynamicSharedMemorySize, 98304) == hipSuccess;

  if (big){
    gemm256<0,256><<<dim3(MTOT/256, 3*D_EMB/256), 512, 131072, stream>>>(h1, WqkvT, MTOT, 3*D_EMB, D_EMB,
        bq, bk, bv, nullptr, Qb, Kb, VTb);
    attn_kernel<<<NB*NH*(NSEQ/128), 256, 0, stream>>>(Qb, Kb, VTb, attnC);
    gemm256<1,128><<<dim3(MTOT/256, D_EMB/128), 512, 98304, stream>>>(attnC, WpT, MTOT, D_EMB, D_EMB,
        bp, nullptr, nullptr, x, x1, nullptr, nullptr);
    ln_kernel<<<MTOT, 256, 0, stream>>>(x1, ln2g, ln2b, h2);
    gemm256<2,256><<<dim3(MTOT/256, DFF/256), 512, 131072, stream>>>(h2, W1T, MTOT, DFF, D_EMB,
        b1, nullptr, nullptr, nullptr, ffb, nullptr, nullptr);
    gemm256<1,128><<<dim3(MTOT/256, D_EMB/128), 512, 98304, stream>>>(ffb, W2T, MTOT, D_EMB, DFF,
        b2, nullptr, nullptr, x1, out, nullptr, nullptr);
  } else {
    gemm_bt<0><<<dim3(MTOT/BM, (3*D_EMB)/BN), 256, 0, stream>>>(h1, WqkvT, MTOT, 3*D_EMB, D_EMB,
        bq, bk, bv, nullptr, Qb, Kb, VTb);
    attn_kernel<<<NB*NH*(NSEQ/128), 256, 0, stream>>>(Qb, Kb, VTb, attnC);
    gemm_bt<1><<<dim3(MTOT/BM, D_EMB/BN), 256, 0, stream>>>(attnC, WpT, MTOT, D_EMB, D_EMB,
        bp, nullptr, nullptr, x, x1, nullptr, nullptr);
    ln_kernel<<<MTOT, 256, 0, stream>>>(x1, ln2g, ln2b, h2);
    gemm_bt<2><<<dim3(MTOT/BM, DFF/BN), 256, 0, stream>>>(h2, W1T, MTOT, DFF, D_EMB,
        b1, nullptr, nullptr, nullptr, ffb, nullptr, nullptr);
    gemm_bt<1><<<dim3(MTOT/BM, D_EMB/BN), 256, 0, stream>>>(ffb, W2T, MTOT, D_EMB, DFF,
        b2, nullptr, nullptr, x1, out, nullptr, nullptr);
  }
}